// Round 5
// baseline (156.852 us; speedup 1.0000x reference)
//
#include <hip/hip_runtime.h>
#include <cmath>

#define EMBED   1024
#define EPB     8
#define NB      64
#define KTOP    2
#define TPW     8               // tokens per wave-chunk (binned main kernel)

// ---------------------------------------------------------------------------
// Binning kernel (single block, 1024 threads) — round-2-verified machinery:
// LDS histogram -> wave-0 shuffle scan -> LDS-cursor scatter into bucket-major
// perm[], plus chunk->bucket map with TPW-token chunks. No global atomics.
// ---------------------------------------------------------------------------
__global__ __launch_bounds__(1024) void bin_kernel(
    const int* __restrict__ op, int ntok,
    int* __restrict__ bstart_g, int* __restrict__ cnt_g,
    int* __restrict__ cpre_g, int* __restrict__ chunk2b,
    int* __restrict__ perm) {
    __shared__ int s_hist[NB];
    __shared__ int s_cur[NB];
    int tid = threadIdx.x, lane = tid & 63;
    if (tid < NB) s_hist[tid] = 0;
    __syncthreads();
    for (int i = tid; i < ntok; i += 1024) {
        int b = min(max(op[i], 0), NB - 1);
        atomicAdd(&s_hist[b], 1);
    }
    __syncthreads();
    if (tid < 64) {                            // wave 0 exactly
        int c   = s_hist[tid];
        int nch = (c + TPW - 1) / TPW;
        int ic = c, in = nch;                  // inclusive scans
#pragma unroll
        for (int off = 1; off < 64; off <<= 1) {
            int vc = __shfl_up(ic, off, 64);
            int vn = __shfl_up(in, off, 64);
            if (lane >= off) { ic += vc; in += vn; }
        }
        int bs = ic - c;                       // exclusive
        int cp = in - nch;
        s_cur[tid]    = bs;
        bstart_g[tid] = bs;
        cnt_g[tid]    = c;
        cpre_g[tid]   = cp;
        if (tid == 63) cpre_g[NB] = in;        // total chunks
        for (int j = 0; j < nch; ++j) chunk2b[cp + j] = tid;
    }
    __syncthreads();
    for (int i = tid; i < ntok; i += 1024) {
        int b = min(max(op[i], 0), NB - 1);
        int pos = atomicAdd(&s_cur[b], 1);
        perm[pos] = i;
    }
}

// ---------------------------------------------------------------------------
// Main kernel: one WAVE per chunk of TPW=8 same-bucket tokens.
//   - The wave loads its bucket's ENTIRE key set (8 x 1024 floats = 32 KB)
//     into 128 VGPRs with 32 independent coalesced 1 KB loads -> full MLP,
//     paid once per 8 tokens. Kills the per-token L1-miss traffic that
//     pinned every previous structure at ~48 us (~20 B/cyc/CU MSHR ceiling).
//   - Key rnorms computed from those registers: identical element->lane
//     mapping and butterfly order as the verified rnorm kernel (bitwise
//     same numerics) -> separate rnorm kernel deleted.
//   - Per token: 4 coalesced h loads (hv[c] = hrow[c*64+lane]), c-order
//     dot/hh accumulation, 6-stage 64-lane butterfly, round-4 softmax/top-2
//     tail -- all bitwise identical to previously-passing kernels.
//   - launch_bounds(256,2): ~200 VGPR budget, 2 blocks/CU resident; grid of
//     528 blocks = exactly one residency round over 256 CUs.
// ---------------------------------------------------------------------------
__global__ __launch_bounds__(256, 2) void router_regkey_kernel(
    const float* __restrict__ h, const float* __restrict__ ek,
    const int* __restrict__ perm, const int* __restrict__ bstart_g,
    const int* __restrict__ cnt_g, const int* __restrict__ cpre_g,
    const int* __restrict__ chunk2b,
    float* __restrict__ out_gid, float* __restrict__ out_w) {
    int gtid = blockIdx.x * blockDim.x + threadIdx.x;
    int wid  = gtid >> 6;
    int lane = threadIdx.x & 63;
    int total = cpre_g[NB];
    if (wid >= total) return;

    int b    = chunk2b[wid];
    int lc   = wid - cpre_g[b];
    int base = bstart_g[b] + lc * TPW;
    int end  = bstart_g[b] + cnt_g[b];

    // ---- keys -> registers: 32 independent coalesced 1 KB loads ----
    const float4* kb = (const float4*)ek + (size_t)b * (EPB * EMBED / 4);
    float4 kv[EPB * 4];
#pragma unroll
    for (int e = 0; e < EPB; ++e)
#pragma unroll
        for (int i = 0; i < 4; ++i)
            kv[e * 4 + i] = kb[e * 256 + i * 64 + lane];

    // ---- key rnorms from registers (same order as verified rnorm kernel) --
    float rke[EPB];
#pragma unroll
    for (int e = 0; e < EPB; ++e) {
        float s = 0.f;
#pragma unroll
        for (int i = 0; i < 4; ++i) {
            float4 v = kv[e * 4 + i];
            s += v.x * v.x + v.y * v.y + v.z * v.z + v.w * v.w;
        }
        rke[e] = s;
    }
#pragma unroll
    for (int off = 32; off; off >>= 1)
#pragma unroll
        for (int e = 0; e < EPB; ++e) rke[e] += __shfl_xor(rke[e], off, 64);
#pragma unroll
    for (int e = 0; e < EPB; ++e)
        rke[e] = 1.0f / fmaxf(sqrtf(rke[e]), 1e-12f);

    // ---- token indices (wave-uniform broadcast loads) ----
    int tok[TPW];
#pragma unroll
    for (int t = 0; t < TPW; ++t) tok[t] = perm[min(base + t, end - 1)];

    // ---- stream 8 tokens against register keys ----
#pragma unroll
    for (int t = 0; t < TPW; ++t) {
        const float4* hrow = (const float4*)(h + (size_t)tok[t] * EMBED);
        float4 hv[4];
#pragma unroll
        for (int c = 0; c < 4; ++c) hv[c] = hrow[c * 64 + lane];

        float hh = 0.f;
        float dot[EPB] = {0.f, 0.f, 0.f, 0.f, 0.f, 0.f, 0.f, 0.f};
#pragma unroll
        for (int c = 0; c < 4; ++c) {
            float4 a = hv[c];
            hh += a.x * a.x + a.y * a.y + a.z * a.z + a.w * a.w;
#pragma unroll
            for (int e = 0; e < EPB; ++e) {
                float4 k4 = kv[e * 4 + c];
                dot[e] += a.x * k4.x + a.y * k4.y + a.z * k4.z + a.w * k4.w;
            }
        }

        // 6-stage 64-lane butterfly (identical to verified baseline)
#pragma unroll
        for (int off = 32; off; off >>= 1) {
            hh += __shfl_xor(hh, off, 64);
#pragma unroll
            for (int e = 0; e < EPB; ++e) dot[e] += __shfl_xor(dot[e], off, 64);
        }

        // softmax + top-2, redundant on all lanes (round-4 verified tail)
        float rh = 1.0f / fmaxf(sqrtf(hh), 1e-12f);
        float sc[EPB];
        float m = -1e30f;
#pragma unroll
        for (int e = 0; e < EPB; ++e) {
            sc[e] = dot[e] * rh * rke[e];      // TAU = 1.0
            m = fmaxf(m, sc[e]);
        }
        float ex[EPB];
        float Z = 0.f;
#pragma unroll
        for (int e = 0; e < EPB; ++e) { ex[e] = expf(sc[e] - m); Z += ex[e]; }

        int i1 = 0;                            // top-1, lowest index on ties
#pragma unroll
        for (int e = 1; e < EPB; ++e) if (ex[e] > ex[i1]) i1 = e;
        int i2 = (i1 == 0) ? 1 : 0;            // top-2 excluding i1
#pragma unroll
        for (int e = 0; e < EPB; ++e)
            if (e != i1 && ex[e] > ex[i2]) i2 = e;

        if (lane == 0 && (base + t) < end) {
            float p1 = ex[i1] / Z;
            float p2 = ex[i2] / Z;
            float ws = p1 + p2 + 1e-9f;
            int tk = tok[t];
            ((float2*)out_gid)[tk] =
                make_float2((float)(b * EPB + i1), (float)(b * EPB + i2));
            ((float2*)out_w)[tk] = make_float2(p1 / ws, p2 / ws);
        }
    }
}

// ---------------------------------------------------------------------------
// Fallback path (workspace too small): round-4 verified 2-kernel version.
// ---------------------------------------------------------------------------
__global__ void key_rnorm_kernel(const float* __restrict__ ek,
                                 float* __restrict__ rnorm) {
    int wave = (int)((blockIdx.x * blockDim.x + threadIdx.x) >> 6);
    int lane = threadIdx.x & 63;
    if (wave >= NB * EPB) return;
    const float4* row = (const float4*)(ek + (size_t)wave * EMBED);
    float s = 0.f;
#pragma unroll
    for (int c = 0; c < 4; ++c) {
        float4 v = row[c * 64 + lane];
        s += v.x * v.x + v.y * v.y + v.z * v.z + v.w * v.w;
    }
#pragma unroll
    for (int off = 32; off; off >>= 1) s += __shfl_xor(s, off, 64);
    if (lane == 0) rnorm[wave] = 1.0f / fmaxf(sqrtf(s), 1e-12f);
}

__global__ __launch_bounds__(256, 6) void router_duo_kernel(
    const float* __restrict__ h, const int* __restrict__ op,
    const float* __restrict__ ek, const float* __restrict__ rk,
    float* __restrict__ out_gid, float* __restrict__ out_w, int ntok) {
    int gtid = blockIdx.x * blockDim.x + threadIdx.x;
    int wid  = gtid >> 6;
    int lane = threadIdx.x & 63;
    int half = lane >> 5;
    int r    = lane & 31;
    int tq   = wid * 2 + half;
    int tc   = min(tq, ntok - 1);

    int b = op[tc];
    b = min(max(b, 0), NB - 1);

    const float4* hrow = (const float4*)(h + (size_t)tc * EMBED);
    const float4* kb   = (const float4*)ek + (size_t)b * (EPB * EMBED / 4);

    float dot[EPB] = {0.f, 0.f, 0.f, 0.f, 0.f, 0.f, 0.f, 0.f};
    float hh = 0.f;
#pragma unroll
    for (int i = 0; i < 8; ++i) {
        float4 a = hrow[i * 32 + r];
        hh += a.x * a.x + a.y * a.y + a.z * a.z + a.w * a.w;
#pragma unroll
        for (int e = 0; e < EPB; ++e) {
            float4 kvv = kb[e * 256 + i * 32 + r];
            dot[e] += a.x * kvv.x + a.y * kvv.y + a.z * kvv.z + a.w * kvv.w;
        }
    }
#pragma unroll
    for (int off = 16; off; off >>= 1) {
        hh += __shfl_xor(hh, off, 64);
#pragma unroll
        for (int e = 0; e < EPB; ++e) dot[e] += __shfl_xor(dot[e], off, 64);
    }
    float rh = 1.0f / fmaxf(sqrtf(hh), 1e-12f);
    float sc[EPB];
    float m = -1e30f;
#pragma unroll
    for (int e = 0; e < EPB; ++e) {
        sc[e] = dot[e] * rh * rk[b * EPB + e];
        m = fmaxf(m, sc[e]);
    }
    float ex[EPB];
    float Z = 0.f;
#pragma unroll
    for (int e = 0; e < EPB; ++e) { ex[e] = expf(sc[e] - m); Z += ex[e]; }
    int i1 = 0;
#pragma unroll
    for (int e = 1; e < EPB; ++e) if (ex[e] > ex[i1]) i1 = e;
    int i2 = (i1 == 0) ? 1 : 0;
#pragma unroll
    for (int e = 0; e < EPB; ++e)
        if (e != i1 && ex[e] > ex[i2]) i2 = e;
    if (r == 0 && tq < ntok) {
        float p1 = ex[i1] / Z;
        float p2 = ex[i2] / Z;
        float ws = p1 + p2 + 1e-9f;
        ((float2*)out_gid)[tq] =
            make_float2((float)(b * EPB + i1), (float)(b * EPB + i2));
        ((float2*)out_w)[tq] = make_float2(p1 / ws, p2 / ws);
    }
}

extern "C" void kernel_launch(void* const* d_in, const int* in_sizes, int n_in,
                              void* d_out, int out_size, void* d_ws, size_t ws_size,
                              hipStream_t stream) {
    const float* h     = (const float*)d_in[0];
    const int*   op_id = (const int*)  d_in[1];
    const float* ek    = (const float*)d_in[2];

    int ntok  = in_sizes[1];                   // B*T tokens
    int maxch = NB + (ntok + TPW - 1) / TPW;   // upper bound on chunks

    float* out_gid = (float*)d_out;
    float* out_w   = out_gid + (size_t)ntok * KTOP;

    // Workspace: rk[512] (fallback) | bstart[64] | cnt[64] | cpre[65]
    //            | chunk2b[maxch] | perm[ntok]
    float* rk      = (float*)d_ws;
    int*   bstart  = (int*)(rk + 512);
    int*   cnt     = bstart + NB;
    int*   cpre    = cnt + NB;
    int*   chunk2b = cpre + (NB + 1);
    int*   perm    = chunk2b + maxch;
    size_t need    = ((size_t)(512 + 2 * NB + NB + 1 + maxch) + (size_t)ntok) * 4;

    if (ws_size < need) {
        key_rnorm_kernel<<<128, 256, 0, stream>>>(ek, rk);
        int blocks2 = (ntok + 7) / 8;
        router_duo_kernel<<<blocks2, 256, 0, stream>>>(h, op_id, ek, rk,
                                                       out_gid, out_w, ntok);
        return;
    }

    // 1: binning (single block)
    bin_kernel<<<1, 1024, 0, stream>>>(op_id, ntok, bstart, cnt, cpre,
                                       chunk2b, perm);
    // 2: register-key router, one wave per chunk
    int blocks = (maxch * 64 + 255) / 256;
    router_regkey_kernel<<<blocks, 256, 0, stream>>>(
        h, ek, perm, bstart, cnt, cpre, chunk2b, out_gid, out_w);
}

// Round 6
// 131.088 us; speedup vs baseline: 1.1965x; 1.1965x over previous
//
#include <hip/hip_runtime.h>
#include <cmath>

#define EMBED   1024
#define EPB     8
#define NB      64
#define KTOP    2
#define TPW     8               // tokens per wave-chunk (binned main kernel)

// ---------------------------------------------------------------------------
// Binning kernel (single block, 1024 threads) — verbatim from round 5
// (passed): LDS histogram -> wave-0 shuffle scan -> LDS-cursor scatter into
// bucket-major perm[], plus chunk->bucket map with TPW-token chunks.
// ---------------------------------------------------------------------------
__global__ __launch_bounds__(1024) void bin_kernel(
    const int* __restrict__ op, int ntok,
    int* __restrict__ bstart_g, int* __restrict__ cnt_g,
    int* __restrict__ cpre_g, int* __restrict__ chunk2b,
    int* __restrict__ perm) {
    __shared__ int s_hist[NB];
    __shared__ int s_cur[NB];
    int tid = threadIdx.x, lane = tid & 63;
    if (tid < NB) s_hist[tid] = 0;
    __syncthreads();
    for (int i = tid; i < ntok; i += 1024) {
        int b = min(max(op[i], 0), NB - 1);
        atomicAdd(&s_hist[b], 1);
    }
    __syncthreads();
    if (tid < 64) {                            // wave 0 exactly
        int c   = s_hist[tid];
        int nch = (c + TPW - 1) / TPW;
        int ic = c, in = nch;                  // inclusive scans
#pragma unroll
        for (int off = 1; off < 64; off <<= 1) {
            int vc = __shfl_up(ic, off, 64);
            int vn = __shfl_up(in, off, 64);
            if (lane >= off) { ic += vc; in += vn; }
        }
        int bs = ic - c;                       // exclusive
        int cp = in - nch;
        s_cur[tid]    = bs;
        bstart_g[tid] = bs;
        cnt_g[tid]    = c;
        cpre_g[tid]   = cp;
        if (tid == 63) cpre_g[NB] = in;        // total chunks
        for (int j = 0; j < nch; ++j) chunk2b[cp + j] = tid;
    }
    __syncthreads();
    for (int i = tid; i < ntok; i += 1024) {
        int b = min(max(op[i], 0), NB - 1);
        int pos = atomicAdd(&s_cur[b], 1);
        perm[pos] = i;
    }
}

// ---------------------------------------------------------------------------
// Spill-proof macro-generated state: 32 named float4 key registers, named
// dot/norm/exp scalars. No arrays, no runtime indexing on the hot path —
// round 5 showed LLVM demotes arrays (dot[8] -> 8 KB LDS, kv[32] -> spill)
// under this pressure; named scalars cannot be demoted piecemeal.
// FP expression ordering matches the round-5 PASSED kernel exactly.
// ---------------------------------------------------------------------------
#define LOADK(e) \
    float4 k##e##_0 = kb[(e)*256 +       lane]; \
    float4 k##e##_1 = kb[(e)*256 +  64 + lane]; \
    float4 k##e##_2 = kb[(e)*256 + 128 + lane]; \
    float4 k##e##_3 = kb[(e)*256 + 192 + lane];

#define SQE(e) \
    float s##e = k##e##_0.x*k##e##_0.x + k##e##_0.y*k##e##_0.y + k##e##_0.z*k##e##_0.z + k##e##_0.w*k##e##_0.w; \
    s##e += k##e##_1.x*k##e##_1.x + k##e##_1.y*k##e##_1.y + k##e##_1.z*k##e##_1.z + k##e##_1.w*k##e##_1.w; \
    s##e += k##e##_2.x*k##e##_2.x + k##e##_2.y*k##e##_2.y + k##e##_2.z*k##e##_2.z + k##e##_2.w*k##e##_2.w; \
    s##e += k##e##_3.x*k##e##_3.x + k##e##_3.y*k##e##_3.y + k##e##_3.z*k##e##_3.z + k##e##_3.w*k##e##_3.w;

#define REDS(off) \
    s0 += __shfl_xor(s0, off, 64); s1 += __shfl_xor(s1, off, 64); \
    s2 += __shfl_xor(s2, off, 64); s3 += __shfl_xor(s3, off, 64); \
    s4 += __shfl_xor(s4, off, 64); s5 += __shfl_xor(s5, off, 64); \
    s6 += __shfl_xor(s6, off, 64); s7 += __shfl_xor(s7, off, 64);

#define ACC1(e,c) \
    d##e += hv##c.x * k##e##_##c.x + hv##c.y * k##e##_##c.y + \
            hv##c.z * k##e##_##c.z + hv##c.w * k##e##_##c.w;

#define STEP_C(c) \
    hh += hv##c.x*hv##c.x + hv##c.y*hv##c.y + hv##c.z*hv##c.z + hv##c.w*hv##c.w; \
    ACC1(0,c) ACC1(1,c) ACC1(2,c) ACC1(3,c) \
    ACC1(4,c) ACC1(5,c) ACC1(6,c) ACC1(7,c)

#define REDD(off) \
    hh += __shfl_xor(hh, off, 64); \
    d0 += __shfl_xor(d0, off, 64); d1 += __shfl_xor(d1, off, 64); \
    d2 += __shfl_xor(d2, off, 64); d3 += __shfl_xor(d3, off, 64); \
    d4 += __shfl_xor(d4, off, 64); d5 += __shfl_xor(d5, off, 64); \
    d6 += __shfl_xor(d6, off, 64); d7 += __shfl_xor(d7, off, 64);

#define T1(e) if (ex##e > v1) { v1 = ex##e; i1 = (e); }
#define T2(e) if ((e) != i1 && ex##e > v2) { v2 = ex##e; i2 = (e); }

// ---------------------------------------------------------------------------
// Main kernel: ONE WAVE PER BLOCK, one chunk of TPW=8 same-bucket tokens.
// The wave holds its bucket's entire 32 KB key set in 128 named VGPRs
// (32 independent coalesced 1 KB loads), computes key rnorms in-register,
// then streams 8 tokens (4 coalesced h loads each) against the register
// keys. launch_bounds(64,2) -> 256-VGPR budget, ~8 waves/CU; 2112 blocks
// = one residency round over 256 CUs.
// ---------------------------------------------------------------------------
__global__ __launch_bounds__(64, 2) void router_regkey_kernel(
    const float* __restrict__ h, const float* __restrict__ ek,
    const int* __restrict__ perm, const int* __restrict__ bstart_g,
    const int* __restrict__ cnt_g, const int* __restrict__ cpre_g,
    const int* __restrict__ chunk2b,
    float* __restrict__ out_gid, float* __restrict__ out_w) {
    int wid  = blockIdx.x;
    int lane = threadIdx.x;                    // 0..63
    int total = cpre_g[NB];
    if (wid >= total) return;

    int b    = chunk2b[wid];
    int lc   = wid - cpre_g[b];
    int base = bstart_g[b] + lc * TPW;
    int end  = bstart_g[b] + cnt_g[b];

    // ---- keys -> 128 named VGPRs: 32 independent coalesced 1 KB loads ----
    const float4* kb = (const float4*)ek + (size_t)b * (EPB * EMBED / 4);
    LOADK(0) LOADK(1) LOADK(2) LOADK(3) LOADK(4) LOADK(5) LOADK(6) LOADK(7)

    // ---- key rnorms from registers (round-5-verified FP order) ----
    SQE(0) SQE(1) SQE(2) SQE(3) SQE(4) SQE(5) SQE(6) SQE(7)
    REDS(32) REDS(16) REDS(8) REDS(4) REDS(2) REDS(1)
    float rke0 = 1.0f / fmaxf(sqrtf(s0), 1e-12f);
    float rke1 = 1.0f / fmaxf(sqrtf(s1), 1e-12f);
    float rke2 = 1.0f / fmaxf(sqrtf(s2), 1e-12f);
    float rke3 = 1.0f / fmaxf(sqrtf(s3), 1e-12f);
    float rke4 = 1.0f / fmaxf(sqrtf(s4), 1e-12f);
    float rke5 = 1.0f / fmaxf(sqrtf(s5), 1e-12f);
    float rke6 = 1.0f / fmaxf(sqrtf(s6), 1e-12f);
    float rke7 = 1.0f / fmaxf(sqrtf(s7), 1e-12f);

    // ---- token indices (wave-uniform scalar loads) ----
    int tok[TPW];
#pragma unroll
    for (int t = 0; t < TPW; ++t) tok[t] = perm[min(base + t, end - 1)];

    // ---- stream 8 tokens against register keys ----
#pragma unroll
    for (int t = 0; t < TPW; ++t) {
        const float4* hrow = (const float4*)(h + (size_t)tok[t] * EMBED);
        float4 hv0 = hrow[lane];
        float4 hv1 = hrow[ 64 + lane];
        float4 hv2 = hrow[128 + lane];
        float4 hv3 = hrow[192 + lane];

        float hh = 0.f;
        float d0 = 0.f, d1 = 0.f, d2 = 0.f, d3 = 0.f;
        float d4 = 0.f, d5 = 0.f, d6 = 0.f, d7 = 0.f;
        STEP_C(0) STEP_C(1) STEP_C(2) STEP_C(3)

        // 6-stage 64-lane butterfly (hh first, then d0..d7 — verified order)
        REDD(32) REDD(16) REDD(8) REDD(4) REDD(2) REDD(1)

        // softmax + top-2, all named scalars (no runtime-indexed arrays)
        float rh = 1.0f / fmaxf(sqrtf(hh), 1e-12f);
        float sc0 = d0 * rh * rke0, sc1 = d1 * rh * rke1;
        float sc2 = d2 * rh * rke2, sc3 = d3 * rh * rke3;
        float sc4 = d4 * rh * rke4, sc5 = d5 * rh * rke5;
        float sc6 = d6 * rh * rke6, sc7 = d7 * rh * rke7;
        float m = -1e30f;
        m = fmaxf(m, sc0); m = fmaxf(m, sc1); m = fmaxf(m, sc2); m = fmaxf(m, sc3);
        m = fmaxf(m, sc4); m = fmaxf(m, sc5); m = fmaxf(m, sc6); m = fmaxf(m, sc7);
        float ex0 = expf(sc0 - m), ex1 = expf(sc1 - m);
        float ex2 = expf(sc2 - m), ex3 = expf(sc3 - m);
        float ex4 = expf(sc4 - m), ex5 = expf(sc5 - m);
        float ex6 = expf(sc6 - m), ex7 = expf(sc7 - m);
        float Z = 0.f;
        Z += ex0; Z += ex1; Z += ex2; Z += ex3;
        Z += ex4; Z += ex5; Z += ex6; Z += ex7;

        float v1 = ex0; int i1 = 0;            // top-1, lowest index on ties
        T1(1) T1(2) T1(3) T1(4) T1(5) T1(6) T1(7)
        float v2 = (i1 == 0) ? ex1 : ex0;      // top-2 excluding i1
        int   i2 = (i1 == 0) ? 1 : 0;
        T2(0) T2(1) T2(2) T2(3) T2(4) T2(5) T2(6) T2(7)

        if (lane == 0 && (base + t) < end) {
            float p1 = v1 / Z;
            float p2 = v2 / Z;
            float ws = p1 + p2 + 1e-9f;
            int tk = tok[t];
            ((float2*)out_gid)[tk] =
                make_float2((float)(b * EPB + i1), (float)(b * EPB + i2));
            ((float2*)out_w)[tk] = make_float2(p1 / ws, p2 / ws);
        }
    }
}

// ---------------------------------------------------------------------------
// Fallback path (workspace too small): round-4 verified 2-kernel version.
// ---------------------------------------------------------------------------
__global__ void key_rnorm_kernel(const float* __restrict__ ek,
                                 float* __restrict__ rnorm) {
    int wave = (int)((blockIdx.x * blockDim.x + threadIdx.x) >> 6);
    int lane = threadIdx.x & 63;
    if (wave >= NB * EPB) return;
    const float4* row = (const float4*)(ek + (size_t)wave * EMBED);
    float s = 0.f;
#pragma unroll
    for (int c = 0; c < 4; ++c) {
        float4 v = row[c * 64 + lane];
        s += v.x * v.x + v.y * v.y + v.z * v.z + v.w * v.w;
    }
#pragma unroll
    for (int off = 32; off; off >>= 1) s += __shfl_xor(s, off, 64);
    if (lane == 0) rnorm[wave] = 1.0f / fmaxf(sqrtf(s), 1e-12f);
}

__global__ __launch_bounds__(256, 6) void router_duo_kernel(
    const float* __restrict__ h, const int* __restrict__ op,
    const float* __restrict__ ek, const float* __restrict__ rk,
    float* __restrict__ out_gid, float* __restrict__ out_w, int ntok) {
    int gtid = blockIdx.x * blockDim.x + threadIdx.x;
    int wid  = gtid >> 6;
    int lane = threadIdx.x & 63;
    int half = lane >> 5;
    int r    = lane & 31;
    int tq   = wid * 2 + half;
    int tc   = min(tq, ntok - 1);

    int b = op[tc];
    b = min(max(b, 0), NB - 1);

    const float4* hrow = (const float4*)(h + (size_t)tc * EMBED);
    const float4* kb   = (const float4*)ek + (size_t)b * (EPB * EMBED / 4);

    float dot[EPB] = {0.f, 0.f, 0.f, 0.f, 0.f, 0.f, 0.f, 0.f};
    float hh = 0.f;
#pragma unroll
    for (int i = 0; i < 8; ++i) {
        float4 a = hrow[i * 32 + r];
        hh += a.x * a.x + a.y * a.y + a.z * a.z + a.w * a.w;
#pragma unroll
        for (int e = 0; e < EPB; ++e) {
            float4 kvv = kb[e * 256 + i * 32 + r];
            dot[e] += a.x * kvv.x + a.y * kvv.y + a.z * kvv.z + a.w * kvv.w;
        }
    }
#pragma unroll
    for (int off = 16; off; off >>= 1) {
        hh += __shfl_xor(hh, off, 64);
#pragma unroll
        for (int e = 0; e < EPB; ++e) dot[e] += __shfl_xor(dot[e], off, 64);
    }
    float rh = 1.0f / fmaxf(sqrtf(hh), 1e-12f);
    float sc[EPB];
    float m = -1e30f;
#pragma unroll
    for (int e = 0; e < EPB; ++e) {
        sc[e] = dot[e] * rh * rk[b * EPB + e];
        m = fmaxf(m, sc[e]);
    }
    float ex[EPB];
    float Z = 0.f;
#pragma unroll
    for (int e = 0; e < EPB; ++e) { ex[e] = expf(sc[e] - m); Z += ex[e]; }
    int i1 = 0;
#pragma unroll
    for (int e = 1; e < EPB; ++e) if (ex[e] > ex[i1]) i1 = e;
    int i2 = (i1 == 0) ? 1 : 0;
#pragma unroll
    for (int e = 0; e < EPB; ++e)
        if (e != i1 && ex[e] > ex[i2]) i2 = e;
    if (r == 0 && tq < ntok) {
        float p1 = ex[i1] / Z;
        float p2 = ex[i2] / Z;
        float ws = p1 + p2 + 1e-9f;
        ((float2*)out_gid)[tq] =
            make_float2((float)(b * EPB + i1), (float)(b * EPB + i2));
        ((float2*)out_w)[tq] = make_float2(p1 / ws, p2 / ws);
    }
}

extern "C" void kernel_launch(void* const* d_in, const int* in_sizes, int n_in,
                              void* d_out, int out_size, void* d_ws, size_t ws_size,
                              hipStream_t stream) {
    const float* h     = (const float*)d_in[0];
    const int*   op_id = (const int*)  d_in[1];
    const float* ek    = (const float*)d_in[2];

    int ntok  = in_sizes[1];                   // B*T tokens
    int maxch = NB + (ntok + TPW - 1) / TPW;   // upper bound on chunks

    float* out_gid = (float*)d_out;
    float* out_w   = out_gid + (size_t)ntok * KTOP;

    // Workspace: rk[512] (fallback) | bstart[64] | cnt[64] | cpre[65]
    //            | chunk2b[maxch] | perm[ntok]
    float* rk      = (float*)d_ws;
    int*   bstart  = (int*)(rk + 512);
    int*   cnt     = bstart + NB;
    int*   cpre    = cnt + NB;
    int*   chunk2b = cpre + (NB + 1);
    int*   perm    = chunk2b + maxch;
    size_t need    = ((size_t)(512 + 2 * NB + NB + 1 + maxch) + (size_t)ntok) * 4;

    if (ws_size < need) {
        key_rnorm_kernel<<<128, 256, 0, stream>>>(ek, rk);
        int blocks2 = (ntok + 7) / 8;
        router_duo_kernel<<<blocks2, 256, 0, stream>>>(h, op_id, ek, rk,
                                                       out_gid, out_w, ntok);
        return;
    }

    // 1: binning (single block)
    bin_kernel<<<1, 1024, 0, stream>>>(op_id, ntok, bstart, cnt, cpre,
                                       chunk2b, perm);
    // 2: register-key router, ONE WAVE PER BLOCK
    router_regkey_kernel<<<maxch, 64, 0, stream>>>(
        h, ek, perm, bstart, cnt, cpre, chunk2b, out_gid, out_w);
}